// Round 1
// baseline (7077.216 us; speedup 1.0000x reference)
//
#include <hip/hip_runtime.h>
#include <cstdint>
#include <cstddef>

// Problem dims
#define B_  32
#define S_  64
#define T_  32
#define H_  512
#define V_  32000
#define H3_ 1536

// ws offsets (in floats)
#define OFF_HID   0          // [2][32][512]  current hidden (h0, h1)
#define OFF_H0N   32768      // [32][512]     new h0 (double buffer)
#define OFF_H1N   49152      // [32][512]     new h1 (double buffer)
#define OFF_UK    65536      // [32][64][512] Ukeys = enc @ Ua^T + bua
#define OFF_Q     1114112    // [32][512]     q = query @ Wa^T + ba
#define OFF_GIN   1130496    // [32][1024]    [emb, context]
#define OFF_GI0   1163264    // [32][1536]
#define OFF_GH0   1212416    // [32][1536]
#define OFF_GI1   1261568    // [32][1536]
#define OFF_GH1   1310720    // [32][1536]
#define OFF_LSE   1359872    // [32][32]      lse[t][b]
#define OFF_SMAX  1360896    // [2000][32]
#define OFF_SSUM  1424896    // [2000][32]
#define OFF_SIDX  1488896    // [2000][32] (int)
// end: 1552896 floats = 6.22 MB

// d_out offsets (floats)
#define OUT_LOGP  0
#define OUT_HIDN  32768000
#define OUT_ATTN  32800768

__device__ __forceinline__ float sigm(float x){ return 1.f/(1.f + __expf(-x)); }
__device__ __forceinline__ float tanh_(float x){ float e = __expf(2.f*x); return 1.f - 2.f/(e + 1.f); }
__device__ __forceinline__ float dot4(float4 w, float4 h, float a){
  a = fmaf(w.x,h.x,a); a = fmaf(w.y,h.y,a); a = fmaf(w.z,h.z,a); a = fmaf(w.w,h.w,a); return a;
}

// ---------------------------------------------------------------- init
__global__ __launch_bounds__(256) void k_init(const float* __restrict__ ehid, float* __restrict__ ws)
{
  int i = blockIdx.x*256 + threadIdx.x;
  if (i < 2*B_*H_) ws[OFF_HID + i] = ehid[i];
  if (i < B_*H_)   ws[OFF_Q + i] = 0.f;
}

// ---------------------------------------------------------------- Ukeys = enc @ Ua^T + bua  [2048,512]x[512,512]
__global__ __launch_bounds__(256) void k_ukeys(const float* __restrict__ enc, const float* __restrict__ Ua,
                                               const float* __restrict__ bua, float* __restrict__ ws)
{
  __shared__ float As[16][65];
  __shared__ float Bs[16][65];
  int rb = blockIdx.x >> 3, cb = blockIdx.x & 7;
  int row0 = rb*64, col0 = cb*64;
  int tid = threadIdx.x;
  int tx = tid & 15, ty = tid >> 4;
  int lr = tid >> 2, lk = (tid & 3)*4;
  float acc[4][4] = {{0.f}};
  for (int k0 = 0; k0 < 512; k0 += 16){
    float4 a4 = *(const float4*)(enc + (size_t)(row0+lr)*512 + k0 + lk);
    As[lk+0][lr]=a4.x; As[lk+1][lr]=a4.y; As[lk+2][lr]=a4.z; As[lk+3][lr]=a4.w;
    float4 b4 = *(const float4*)(Ua + (size_t)(col0+lr)*512 + k0 + lk);
    Bs[lk+0][lr]=b4.x; Bs[lk+1][lr]=b4.y; Bs[lk+2][lr]=b4.z; Bs[lk+3][lr]=b4.w;
    __syncthreads();
    #pragma unroll
    for (int kk = 0; kk < 16; kk++){
      float a[4], bb[4];
      #pragma unroll
      for (int i=0;i<4;i++) a[i] = As[kk][ty*4+i];
      #pragma unroll
      for (int j=0;j<4;j++) bb[j] = Bs[kk][tx*4+j];
      #pragma unroll
      for (int i=0;i<4;i++)
        #pragma unroll
        for (int j=0;j<4;j++) acc[i][j] = fmaf(a[i], bb[j], acc[i][j]);
    }
    __syncthreads();
  }
  #pragma unroll
  for (int i=0;i<4;i++){
    int r = row0 + ty*4 + i;
    #pragma unroll
    for (int j=0;j<4;j++){
      int c = col0 + tx*4 + j;
      ws[OFF_UK + (size_t)r*512 + c] = acc[i][j] + bua[c];
    }
  }
}

// ---------------------------------------------------------------- stats reduce (token + lse) over 2000 chunks
__device__ void stats_reduce(const float* __restrict__ ws, int b, int tid,
                             float* rm, float* rs, int* ri, int& token, float& lse)
{
  float m = -1e30f, s = 0.f; int idx = 0x7fffffff;
  for (int c = tid; c < 2000; c += 256){
    float cm = ws[OFF_SMAX + c*32 + b];
    float cs = ws[OFF_SSUM + c*32 + b];
    int   ci = ((const int*)ws)[OFF_SIDX + c*32 + b];
    float M = fmaxf(m, cm);
    s = s*__expf(m - M) + cs*__expf(cm - M);
    if (cm > m || (cm == m && ci < idx)) idx = ci;
    m = M;
  }
  rm[tid]=m; rs[tid]=s; ri[tid]=idx;
  __syncthreads();
  for (int off=128; off>0; off>>=1){
    if (tid < off){
      float m1=rm[tid], s1=rs[tid]; int i1=ri[tid];
      float m2=rm[tid+off], s2=rs[tid+off]; int i2=ri[tid+off];
      float M=fmaxf(m1,m2);
      rs[tid] = s1*__expf(m1-M) + s2*__expf(m2-M);
      ri[tid] = (m2 > m1 || (m2==m1 && i2<i1)) ? i2 : i1;
      rm[tid] = M;
    }
    __syncthreads();
  }
  token = ri[0];
  lse = rm[0] + logf(rs[0]);
}

// ---------------------------------------------------------------- attention (one block per b)
// phases: zero gate bufs | stats->token,lse[t-1] | emb->gin | scores | softmax (+attn out) | context->gin
__global__ __launch_bounds__(256) void k_attn(int t, const float* __restrict__ emb,
    const float* __restrict__ enc, const float* __restrict__ Va, const float* __restrict__ bva,
    float* __restrict__ ws, float* __restrict__ out)
{
  int b = blockIdx.x, tid = threadIdx.x;
  for (int i = tid; i < 6144; i += 256) ws[OFF_GI0 + b*6144 + i] = 0.f;  // zero gi0,gh0,gi1,gh1 (contiguous)

  __shared__ float rm[256], rs[256];
  __shared__ int   ri[256];
  __shared__ float sQ[512], sVa[512], sW[64];

  int token; float lse;
  if (t > 0){
    stats_reduce(ws, b, tid, rm, rs, ri, token, lse);
    if (tid == 0) ws[OFF_LSE + (t-1)*32 + b] = lse;
  } else {
    token = 1; // BOS
  }
  for (int i = tid; i < 512; i += 256) ws[OFF_GIN + b*1024 + i] = emb[(size_t)token*512 + i];
  for (int i = tid; i < 512; i += 256){ sQ[i] = ws[OFF_Q + b*512 + i]; sVa[i] = Va[i]; }
  __syncthreads();

  int lane = tid & 63, wv = tid >> 6;
  float bv = bva[0];
  for (int si = 0; si < 16; si++){
    int s = wv*16 + si;
    const float* uk = ws + OFF_UK + ((size_t)b*64 + s)*512 + lane*8;
    const float* qq = sQ + lane*8;
    const float* vv = sVa + lane*8;
    float4 u0 = *(const float4*)(uk), u1 = *(const float4*)(uk+4);
    float p = tanh_(qq[0]+u0.x)*vv[0] + tanh_(qq[1]+u0.y)*vv[1]
            + tanh_(qq[2]+u0.z)*vv[2] + tanh_(qq[3]+u0.w)*vv[3]
            + tanh_(qq[4]+u1.x)*vv[4] + tanh_(qq[5]+u1.y)*vv[5]
            + tanh_(qq[6]+u1.z)*vv[6] + tanh_(qq[7]+u1.w)*vv[7];
    for (int off=32; off; off>>=1) p += __shfl_xor(p, off);
    if (lane == 0) sW[s] = p + bv;
  }
  __syncthreads();
  if (wv == 0){
    float sc = sW[lane];
    float m = sc;
    for (int off=32; off; off>>=1) m = fmaxf(m, __shfl_xor(m, off));
    float e = __expf(sc - m);
    float Ssum = e;
    for (int off=32; off; off>>=1) Ssum += __shfl_xor(Ssum, off);
    float wgt = e / Ssum;
    sW[lane] = wgt;
    out[OUT_ATTN + ((size_t)b*T_ + t)*S_ + lane] = wgt;
  }
  __syncthreads();
  float c0 = 0.f, c1 = 0.f;
  for (int s = 0; s < 64; s++){
    float wgt = sW[s];
    const float* er = enc + ((size_t)b*64 + s)*512;
    c0 = fmaf(wgt, er[tid], c0);
    c1 = fmaf(wgt, er[tid+256], c1);
  }
  ws[OFF_GIN + b*1024 + 512 + tid]       = c0;
  ws[OFF_GIN + b*1024 + 512 + tid + 256] = c1;
}

// ---------------------------------------------------------------- GRU0 gates: gi0 = gin@Wih^T(+bih), gh0 = h0@Whh^T(+bhh)
// grid 96 = 24 colchunks x 4 kslices; atomic accumulate
__global__ __launch_bounds__(256) void k_gates0(const float* __restrict__ Wih, const float* __restrict__ Whh,
    const float* __restrict__ bih, const float* __restrict__ bhh, float* __restrict__ ws)
{
  int cc = blockIdx.x % 24, ks = blockIdx.x / 24;
  int tid = threadIdx.x;
  if (blockIdx.x < 64) ws[OFF_Q + blockIdx.x*256 + tid] = 0.f;  // zero q for next-step accumulation
  __shared__ float gT[256][32];
  __shared__ float hT[128][32];
  {
    int b = tid & 31, kq = tid >> 5;
    for (int it = 0; it < 8; it++){
      int k = it*32 + kq*4;
      float4 v = *(const float4*)(ws + OFF_GIN + b*1024 + ks*256 + k);
      gT[k+0][b]=v.x; gT[k+1][b]=v.y; gT[k+2][b]=v.z; gT[k+3][b]=v.w;
    }
    for (int it = 0; it < 4; it++){
      int k = it*32 + kq*4;
      float4 v = *(const float4*)(ws + OFF_HID + b*512 + ks*128 + k);
      hT[k+0][b]=v.x; hT[k+1][b]=v.y; hT[k+2][b]=v.z; hT[k+3][b]=v.w;
    }
  }
  __syncthreads();
  int lane = tid & 63, wv = tid >> 6;
  int b = lane & 31, ch = lane >> 5;
  int c0 = cc*64 + wv*16 + ch*8;
  float ai[8] = {0,0,0,0,0,0,0,0}, ah[8] = {0,0,0,0,0,0,0,0};
  for (int j = 0; j < 64; j++){
    float4 h4 = { gT[j*4+0][b], gT[j*4+1][b], gT[j*4+2][b], gT[j*4+3][b] };
    #pragma unroll
    for (int vv = 0; vv < 8; vv++){
      float4 w4 = *(const float4*)(Wih + (size_t)(c0+vv)*1024 + ks*256 + j*4);
      ai[vv] = dot4(w4, h4, ai[vv]);
    }
  }
  for (int j = 0; j < 32; j++){
    float4 h4 = { hT[j*4+0][b], hT[j*4+1][b], hT[j*4+2][b], hT[j*4+3][b] };
    #pragma unroll
    for (int vv = 0; vv < 8; vv++){
      float4 w4 = *(const float4*)(Whh + (size_t)(c0+vv)*512 + ks*128 + j*4);
      ah[vv] = dot4(w4, h4, ah[vv]);
    }
  }
  #pragma unroll
  for (int vv = 0; vv < 8; vv++){
    float a = ai[vv] + (ks==0 ? bih[c0+vv] : 0.f);
    float h = ah[vv] + (ks==0 ? bhh[c0+vv] : 0.f);
    atomicAdd(ws + OFF_GI0 + b*H3_ + c0 + vv, a);
    atomicAdd(ws + OFF_GH0 + b*H3_ + c0 + vv, h);
  }
}

// ---------------------------------------------------------------- GRU1 gates (with inline h0-combine); grid 96
__global__ __launch_bounds__(256) void k_gates1(const float* __restrict__ Wih, const float* __restrict__ Whh,
    const float* __restrict__ bih, const float* __restrict__ bhh, float* __restrict__ ws)
{
  int cc = blockIdx.x % 24, ks = blockIdx.x / 24; // k-slice of 128
  int tid = threadIdx.x;
  __shared__ float h0T[128][32];
  __shared__ float h1T[128][32];
  for (int i = tid; i < 4096; i += 256){
    int b = i & 31, kk = i >> 5;
    int k = ks*128 + kk;
    float ir = ws[OFF_GI0 + b*H3_ + k],         hr = ws[OFF_GH0 + b*H3_ + k];
    float iz = ws[OFF_GI0 + b*H3_ + 512 + k],   hz = ws[OFF_GH0 + b*H3_ + 512 + k];
    float in_= ws[OFF_GI0 + b*H3_ + 1024 + k],  hn = ws[OFF_GH0 + b*H3_ + 1024 + k];
    float r = sigm(ir + hr), z = sigm(iz + hz);
    float n = tanh_(in_ + r*hn);
    float h0 = (1.f - z)*n + z*ws[OFF_HID + b*512 + k];
    h0T[kk][b] = h0;
    if (cc == 0) ws[OFF_H0N + b*512 + k] = h0;
  }
  {
    int b = tid & 31, kq = tid >> 5;
    for (int it = 0; it < 4; it++){
      int k = it*32 + kq*4;
      float4 v = *(const float4*)(ws + OFF_HID + 16384 + b*512 + ks*128 + k);
      h1T[k+0][b]=v.x; h1T[k+1][b]=v.y; h1T[k+2][b]=v.z; h1T[k+3][b]=v.w;
    }
  }
  __syncthreads();
  int lane = tid & 63, wv = tid >> 6;
  int b = lane & 31, ch = lane >> 5;
  int c0 = cc*64 + wv*16 + ch*8;
  float ai[8] = {0,0,0,0,0,0,0,0}, ah[8] = {0,0,0,0,0,0,0,0};
  for (int j = 0; j < 32; j++){
    float4 a4 = { h0T[j*4+0][b], h0T[j*4+1][b], h0T[j*4+2][b], h0T[j*4+3][b] };
    float4 b4 = { h1T[j*4+0][b], h1T[j*4+1][b], h1T[j*4+2][b], h1T[j*4+3][b] };
    #pragma unroll
    for (int vv = 0; vv < 8; vv++){
      float4 wi = *(const float4*)(Wih + (size_t)(c0+vv)*512 + ks*128 + j*4);
      ai[vv] = dot4(wi, a4, ai[vv]);
      float4 wh = *(const float4*)(Whh + (size_t)(c0+vv)*512 + ks*128 + j*4);
      ah[vv] = dot4(wh, b4, ah[vv]);
    }
  }
  #pragma unroll
  for (int vv = 0; vv < 8; vv++){
    float a = ai[vv] + (ks==0 ? bih[c0+vv] : 0.f);
    float h = ah[vv] + (ks==0 ? bhh[c0+vv] : 0.f);
    atomicAdd(ws + OFF_GI1 + b*H3_ + c0 + vv, a);
    atomicAdd(ws + OFF_GH1 + b*H3_ + c0 + vv, h);
  }
}

// ---------------------------------------------------------------- h1-combine + q gemm for NEXT step; grid 32 = 8cc x 4ks
__global__ __launch_bounds__(256) void k_hq(int init, const float* __restrict__ Wa,
    const float* __restrict__ ba, float* __restrict__ ws)
{
  int cc = blockIdx.x & 7, ks = blockIdx.x >> 3; // k-slice of 256 (of 1024 query dims)
  int tid = threadIdx.x;
  __shared__ float qT[256][32];
  if (!init && ks >= 2){
    for (int i = tid; i < 8192; i += 256){
      int b = i & 31, kk = i >> 5;
      int k = (ks - 2)*256 + kk;
      float ir = ws[OFF_GI1 + b*H3_ + k],        hr = ws[OFF_GH1 + b*H3_ + k];
      float iz = ws[OFF_GI1 + b*H3_ + 512 + k],  hz = ws[OFF_GH1 + b*H3_ + 512 + k];
      float in_= ws[OFF_GI1 + b*H3_ + 1024 + k], hn = ws[OFF_GH1 + b*H3_ + 1024 + k];
      float r = sigm(ir+hr), z = sigm(iz+hz);
      float n = tanh_(in_ + r*hn);
      float h1 = (1.f - z)*n + z*ws[OFF_HID + 16384 + b*512 + k];
      qT[kk][b] = h1;
      if (cc == 0) ws[OFF_H1N + b*512 + k] = h1;
    }
  } else {
    int b = tid & 31, kq = tid >> 5;
    const float* src;
    if (init) src = ws + OFF_HID + (ks >> 1)*16384 + (ks & 1)*256;
    else      src = ws + OFF_H0N + ks*256;
    for (int it = 0; it < 8; it++){
      int k = it*32 + kq*4;
      float4 v = *(const float4*)(src + b*512 + k);
      qT[k+0][b]=v.x; qT[k+1][b]=v.y; qT[k+2][b]=v.z; qT[k+3][b]=v.w;
    }
  }
  // designated copy of new h0 into hidden[0] (non-init, low half): racing nothing (readers use H0N)
  if (!init && ks < 2 && cc == 0){
    for (int i = tid; i < 8192; i += 256){
      int b = i & 31, kk = i >> 5;
      ws[OFF_HID + b*512 + ks*256 + kk] = ws[OFF_H0N + b*512 + ks*256 + kk];
    }
  }
  __syncthreads();
  int lane = tid & 63, wv = tid >> 6;
  int b = lane & 31, ch = lane >> 5;
  int c0 = cc*64 + wv*16 + ch*8;
  float acc[8] = {0,0,0,0,0,0,0,0};
  for (int j = 0; j < 64; j++){
    float4 h4 = { qT[j*4+0][b], qT[j*4+1][b], qT[j*4+2][b], qT[j*4+3][b] };
    #pragma unroll
    for (int vv = 0; vv < 8; vv++){
      float4 w4 = *(const float4*)(Wa + (size_t)(c0+vv)*1024 + ks*256 + j*4);
      acc[vv] = dot4(w4, h4, acc[vv]);
    }
  }
  #pragma unroll
  for (int vv = 0; vv < 8; vv++)
    atomicAdd(ws + OFF_Q + b*512 + c0 + vv, acc[vv] + (ks==0 ? ba[c0+vv] : 0.f));
}

// ---------------------------------------------------------------- logits + chunk stats; grid 500, writes raw logits to d_out
__global__ __launch_bounds__(256) void k_logits(int t, const float* __restrict__ outW,
    const float* __restrict__ outb, float* __restrict__ ws, float* __restrict__ out)
{
  __shared__ float hT[512][32]; // 64 KB
  int tid = threadIdx.x;
  if (blockIdx.x == 0){
    for (int i = tid; i < 16384; i += 256) ws[OFF_HID + 16384 + i] = ws[OFF_H1N + i];
  }
  {
    int b = tid & 31, kq = tid >> 5;
    for (int it = 0; it < 16; it++){
      int k = it*32 + kq*4;
      float4 v = *(const float4*)(ws + OFF_H1N + b*512 + k);
      hT[k+0][b]=v.x; hT[k+1][b]=v.y; hT[k+2][b]=v.z; hT[k+3][b]=v.w;
    }
  }
  __syncthreads();
  int lane = tid & 63, wv = tid >> 6;
  int b = lane & 31, vh = lane >> 5;
  int v0 = blockIdx.x*64 + wv*16 + vh*8;
  const float* w0 = outW + (size_t)v0*512;
  float acc[8] = {0,0,0,0,0,0,0,0};
  for (int j = 0; j < 128; j++){
    float4 h4 = { hT[j*4+0][b], hT[j*4+1][b], hT[j*4+2][b], hT[j*4+3][b] };
    #pragma unroll
    for (int vv = 0; vv < 8; vv++){
      float4 w4 = *(const float4*)(w0 + vv*512 + j*4);
      acc[vv] = dot4(w4, h4, acc[vv]);
    }
  }
  float vals[8];
  #pragma unroll
  for (int vv = 0; vv < 8; vv++) vals[vv] = acc[vv] + outb[v0+vv];
  float* orow = out + OUT_LOGP + ((size_t)b*T_ + t)*V_ + v0;
  float4 o0 = {vals[0],vals[1],vals[2],vals[3]};
  float4 o1 = {vals[4],vals[5],vals[6],vals[7]};
  *(float4*)(orow)     = o0;
  *(float4*)(orow + 4) = o1;
  float m = vals[0]; int mi = v0;
  #pragma unroll
  for (int vv = 1; vv < 8; vv++){ if (vals[vv] > m){ m = vals[vv]; mi = v0+vv; } }
  float se = 0.f;
  #pragma unroll
  for (int vv = 0; vv < 8; vv++) se += __expf(vals[vv] - m);
  float m2 = __shfl_xor(m, 32);
  float s2 = __shfl_xor(se, 32);
  int   i2 = __shfl_xor(mi, 32);
  float M = fmaxf(m, m2);
  se = se*__expf(m-M) + s2*__expf(m2-M);
  mi = (m2 > m || (m2 == m && i2 < mi)) ? i2 : mi;
  if (lane < 32){
    int chunk = blockIdx.x*4 + wv;
    ws[OFF_SMAX + chunk*32 + b] = M;
    ws[OFF_SSUM + chunk*32 + b] = se;
    ((int*)ws)[OFF_SIDX + chunk*32 + b] = mi;
  }
}

// ---------------------------------------------------------------- final stats (step 31 lse)
__global__ __launch_bounds__(256) void k_finstats(float* __restrict__ ws)
{
  __shared__ float rm[256], rs[256];
  __shared__ int   ri[256];
  int b = blockIdx.x; int token; float lse;
  stats_reduce(ws, b, threadIdx.x, rm, rs, ri, token, lse);
  if (threadIdx.x == 0) ws[OFF_LSE + 31*32 + b] = lse;
}

// ---------------------------------------------------------------- logits -> log_probs in place + final hidden copy
__global__ __launch_bounds__(256) void k_finout(const float* __restrict__ ws, float* __restrict__ out)
{
  if (blockIdx.x < 16000){
    size_t base = (size_t)blockIdx.x*2048 + (size_t)threadIdx.x*8;
    int b = (int)(base / ((size_t)T_*V_));
    int t = (int)((base / V_) % T_);
    float lse = ws[OFF_LSE + t*32 + b];
    float4* p = (float4*)(out + base);
    float4 x = p[0], y = p[1];
    x.x-=lse; x.y-=lse; x.z-=lse; x.w-=lse;
    y.x-=lse; y.y-=lse; y.z-=lse; y.w-=lse;
    p[0]=x; p[1]=y;
  } else {
    int i = (blockIdx.x - 16000)*2048 + threadIdx.x*8;
    const float4* s = (const float4*)(ws + OFF_HID + i);
    float4* d = (float4*)(out + OUT_HIDN + i);
    d[0] = s[0]; d[1] = s[1];
  }
}

// ---------------------------------------------------------------- launch
extern "C" void kernel_launch(void* const* d_in, const int* in_sizes, int n_in,
                              void* d_out, int out_size, void* d_ws, size_t ws_size,
                              hipStream_t stream)
{
  (void)in_sizes; (void)n_in; (void)out_size; (void)ws_size;
  const float* enc   = (const float*)d_in[0];
  const float* ehid  = (const float*)d_in[1];
  const float* emb   = (const float*)d_in[3];
  const float* Wa    = (const float*)d_in[4];
  const float* ba    = (const float*)d_in[5];
  const float* Ua    = (const float*)d_in[6];
  const float* bua   = (const float*)d_in[7];
  const float* Va    = (const float*)d_in[8];
  const float* bva   = (const float*)d_in[9];
  const float* g0Wih = (const float*)d_in[10];
  const float* g0Whh = (const float*)d_in[11];
  const float* g0bih = (const float*)d_in[12];
  const float* g0bhh = (const float*)d_in[13];
  const float* g1Wih = (const float*)d_in[14];
  const float* g1Whh = (const float*)d_in[15];
  const float* g1bih = (const float*)d_in[16];
  const float* g1bhh = (const float*)d_in[17];
  const float* outW  = (const float*)d_in[18];
  const float* outb  = (const float*)d_in[19];
  float* ws  = (float*)d_ws;
  float* out = (float*)d_out;

  hipLaunchKernelGGL(k_init,   dim3(128), dim3(256), 0, stream, ehid, ws);
  hipLaunchKernelGGL(k_ukeys,  dim3(256), dim3(256), 0, stream, enc, Ua, bua, ws);
  hipLaunchKernelGGL(k_hq,     dim3(32),  dim3(256), 0, stream, 1, Wa, ba, ws);
  for (int t = 0; t < T_; t++){
    hipLaunchKernelGGL(k_attn,   dim3(32),  dim3(256), 0, stream, t, emb, enc, Va, bva, ws, out);
    hipLaunchKernelGGL(k_gates0, dim3(96),  dim3(256), 0, stream, g0Wih, g0Whh, g0bih, g0bhh, ws);
    hipLaunchKernelGGL(k_gates1, dim3(96),  dim3(256), 0, stream, g1Wih, g1Whh, g1bih, g1bhh, ws);
    hipLaunchKernelGGL(k_hq,     dim3(32),  dim3(256), 0, stream, 0, Wa, ba, ws);
    hipLaunchKernelGGL(k_logits, dim3(500), dim3(256), 0, stream, t, outW, outb, ws, out);
  }
  hipLaunchKernelGGL(k_finstats, dim3(32),    dim3(256), 0, stream, ws);
  hipLaunchKernelGGL(k_finout,   dim3(16016), dim3(256), 0, stream, ws, out);
}

// Round 2
// 5990.625 us; speedup vs baseline: 1.1814x; 1.1814x over previous
//
#include <hip/hip_runtime.h>
#include <cstdint>
#include <cstddef>

// Problem dims
#define B_  32
#define S_  64
#define T_  32
#define H_  512
#define V_  32000
#define H3_ 1536

// ws offsets (in floats)
#define OFF_HID   0          // [2][32][512]  current hidden (h0, h1)
#define OFF_H0N   32768      // [32][512]     new h0 (double buffer)
#define OFF_H1N   49152      // [32][512]     new h1 (double buffer)
#define OFF_UK    65536      // [32][64][512] Ukeys = enc @ Ua^T + bua
#define OFF_Q     1114112    // [32][512]     q = query @ Wa^T + ba
#define OFF_GIN   1130496    // [32][1024]    [emb, context]
#define OFF_GI0   1163264    // [32][1536]
#define OFF_GH0   1212416    // [32][1536]
#define OFF_GI1   1261568    // [32][1536]
#define OFF_GH1   1310720    // [32][1536]
#define OFF_LSE   1359872    // [32][32]      lse[t][b]
#define OFF_SMAX  1360896    // [2000][32]
#define OFF_SSUM  1424896    // [2000][32]
#define OFF_SIDX  1488896    // [2000][32] (int)
// end: 1552896 floats = 6.22 MB

// d_out offsets (floats)
#define OUT_LOGP  0
#define OUT_HIDN  32768000
#define OUT_ATTN  32800768

__device__ __forceinline__ float sigm(float x){ return 1.f/(1.f + __expf(-x)); }
__device__ __forceinline__ float tanh_(float x){ float e = __expf(2.f*x); return 1.f - 2.f/(e + 1.f); }
__device__ __forceinline__ float dot4(float4 w, float4 h, float a){
  a = fmaf(w.x,h.x,a); a = fmaf(w.y,h.y,a); a = fmaf(w.z,h.z,a); a = fmaf(w.w,h.w,a); return a;
}

// ---------------------------------------------------------------- init
__global__ __launch_bounds__(256) void k_init(const float* __restrict__ ehid, float* __restrict__ ws)
{
  int i = blockIdx.x*256 + threadIdx.x;
  if (i < 2*B_*H_) ws[OFF_HID + i] = ehid[i];
  if (i < B_*H_)   ws[OFF_Q + i] = 0.f;
}

// ---------------------------------------------------------------- Ukeys = enc @ Ua^T + bua  [2048,512]x[512,512]
__global__ __launch_bounds__(256) void k_ukeys(const float* __restrict__ enc, const float* __restrict__ Ua,
                                               const float* __restrict__ bua, float* __restrict__ ws)
{
  __shared__ float As[16][65];
  __shared__ float Bs[16][65];
  int rb = blockIdx.x >> 3, cb = blockIdx.x & 7;
  int row0 = rb*64, col0 = cb*64;
  int tid = threadIdx.x;
  int tx = tid & 15, ty = tid >> 4;
  int lr = tid >> 2, lk = (tid & 3)*4;
  float acc[4][4] = {{0.f}};
  for (int k0 = 0; k0 < 512; k0 += 16){
    float4 a4 = *(const float4*)(enc + (size_t)(row0+lr)*512 + k0 + lk);
    As[lk+0][lr]=a4.x; As[lk+1][lr]=a4.y; As[lk+2][lr]=a4.z; As[lk+3][lr]=a4.w;
    float4 b4 = *(const float4*)(Ua + (size_t)(col0+lr)*512 + k0 + lk);
    Bs[lk+0][lr]=b4.x; Bs[lk+1][lr]=b4.y; Bs[lk+2][lr]=b4.z; Bs[lk+3][lr]=b4.w;
    __syncthreads();
    #pragma unroll
    for (int kk = 0; kk < 16; kk++){
      float a[4], bb[4];
      #pragma unroll
      for (int i=0;i<4;i++) a[i] = As[kk][ty*4+i];
      #pragma unroll
      for (int j=0;j<4;j++) bb[j] = Bs[kk][tx*4+j];
      #pragma unroll
      for (int i=0;i<4;i++)
        #pragma unroll
        for (int j=0;j<4;j++) acc[i][j] = fmaf(a[i], bb[j], acc[i][j]);
    }
    __syncthreads();
  }
  #pragma unroll
  for (int i=0;i<4;i++){
    int r = row0 + ty*4 + i;
    #pragma unroll
    for (int j=0;j<4;j++){
      int c = col0 + tx*4 + j;
      ws[OFF_UK + (size_t)r*512 + c] = acc[i][j] + bua[c];
    }
  }
}

// ---------------------------------------------------------------- stats reduce (token + lse) over 2000 chunks
__device__ void stats_reduce(const float* __restrict__ ws, int b, int tid,
                             float* rm, float* rs, int* ri, int& token, float& lse)
{
  float m = -1e30f, s = 0.f; int idx = 0x7fffffff;
  for (int c = tid; c < 2000; c += 256){
    float cm = ws[OFF_SMAX + c*32 + b];
    float cs = ws[OFF_SSUM + c*32 + b];
    int   ci = ((const int*)ws)[OFF_SIDX + c*32 + b];
    float M = fmaxf(m, cm);
    s = s*__expf(m - M) + cs*__expf(cm - M);
    if (cm > m || (cm == m && ci < idx)) idx = ci;
    m = M;
  }
  rm[tid]=m; rs[tid]=s; ri[tid]=idx;
  __syncthreads();
  for (int off=128; off>0; off>>=1){
    if (tid < off){
      float m1=rm[tid], s1=rs[tid]; int i1=ri[tid];
      float m2=rm[tid+off], s2=rs[tid+off]; int i2=ri[tid+off];
      float M=fmaxf(m1,m2);
      rs[tid] = s1*__expf(m1-M) + s2*__expf(m2-M);
      ri[tid] = (m2 > m1 || (m2==m1 && i2<i1)) ? i2 : i1;
      rm[tid] = M;
    }
    __syncthreads();
  }
  token = ri[0];
  lse = rm[0] + logf(rs[0]);
}

// ---------------------------------------------------------------- attention (one block per b)
__global__ __launch_bounds__(256) void k_attn(int t, const float* __restrict__ emb,
    const float* __restrict__ enc, const float* __restrict__ Va, const float* __restrict__ bva,
    float* __restrict__ ws, float* __restrict__ out)
{
  int b = blockIdx.x, tid = threadIdx.x;
  for (int i = tid; i < 6144; i += 256) ws[OFF_GI0 + b*6144 + i] = 0.f;  // zero gi0,gh0,gi1,gh1

  __shared__ float rm[256], rs[256];
  __shared__ int   ri[256];
  __shared__ float sQ[512], sVa[512], sW[64];

  int token; float lse;
  if (t > 0){
    stats_reduce(ws, b, tid, rm, rs, ri, token, lse);
    if (tid == 0) ws[OFF_LSE + (t-1)*32 + b] = lse;
  } else {
    token = 1; // BOS
  }
  for (int i = tid; i < 512; i += 256) ws[OFF_GIN + b*1024 + i] = emb[(size_t)token*512 + i];
  for (int i = tid; i < 512; i += 256){ sQ[i] = ws[OFF_Q + b*512 + i]; sVa[i] = Va[i]; }
  __syncthreads();

  int lane = tid & 63, wv = tid >> 6;
  float bv = bva[0];
  for (int si = 0; si < 16; si++){
    int s = wv*16 + si;
    const float* uk = ws + OFF_UK + ((size_t)b*64 + s)*512 + lane*8;
    const float* qq = sQ + lane*8;
    const float* vv = sVa + lane*8;
    float4 u0 = *(const float4*)(uk), u1 = *(const float4*)(uk+4);
    float p = tanh_(qq[0]+u0.x)*vv[0] + tanh_(qq[1]+u0.y)*vv[1]
            + tanh_(qq[2]+u0.z)*vv[2] + tanh_(qq[3]+u0.w)*vv[3]
            + tanh_(qq[4]+u1.x)*vv[4] + tanh_(qq[5]+u1.y)*vv[5]
            + tanh_(qq[6]+u1.z)*vv[6] + tanh_(qq[7]+u1.w)*vv[7];
    for (int off=32; off; off>>=1) p += __shfl_xor(p, off);
    if (lane == 0) sW[s] = p + bv;
  }
  __syncthreads();
  if (wv == 0){
    float sc = sW[lane];
    float m = sc;
    for (int off=32; off; off>>=1) m = fmaxf(m, __shfl_xor(m, off));
    float e = __expf(sc - m);
    float Ssum = e;
    for (int off=32; off; off>>=1) Ssum += __shfl_xor(Ssum, off);
    float wgt = e / Ssum;
    sW[lane] = wgt;
    out[OUT_ATTN + ((size_t)b*T_ + t)*S_ + lane] = wgt;
  }
  __syncthreads();
  float c0 = 0.f, c1 = 0.f;
  for (int s = 0; s < 64; s++){
    float wgt = sW[s];
    const float* er = enc + ((size_t)b*64 + s)*512;
    c0 = fmaf(wgt, er[tid], c0);
    c1 = fmaf(wgt, er[tid+256], c1);
  }
  ws[OFF_GIN + b*1024 + 512 + tid]       = c0;
  ws[OFF_GIN + b*1024 + 512 + tid + 256] = c1;
}

// ---------------------------------------------------------------- GRU0 gates; grid 96 = 24cc x 4ks; atomic accumulate
__global__ __launch_bounds__(256) void k_gates0(const float* __restrict__ Wih, const float* __restrict__ Whh,
    const float* __restrict__ bih, const float* __restrict__ bhh, float* __restrict__ ws)
{
  int cc = blockIdx.x % 24, ks = blockIdx.x / 24;
  int tid = threadIdx.x;
  if (blockIdx.x < 64) ws[OFF_Q + blockIdx.x*256 + tid] = 0.f;  // zero q for next-step accumulation
  __shared__ float gT[256][32];
  __shared__ float hT[128][32];
  {
    int b = tid & 31, kq = tid >> 5;
    for (int it = 0; it < 8; it++){
      int k = it*32 + kq*4;
      float4 v = *(const float4*)(ws + OFF_GIN + b*1024 + ks*256 + k);
      gT[k+0][b]=v.x; gT[k+1][b]=v.y; gT[k+2][b]=v.z; gT[k+3][b]=v.w;
    }
    for (int it = 0; it < 4; it++){
      int k = it*32 + kq*4;
      float4 v = *(const float4*)(ws + OFF_HID + b*512 + ks*128 + k);
      hT[k+0][b]=v.x; hT[k+1][b]=v.y; hT[k+2][b]=v.z; hT[k+3][b]=v.w;
    }
  }
  __syncthreads();
  int lane = tid & 63, wv = tid >> 6;
  int b = lane & 31, ch = lane >> 5;
  int c0 = cc*64 + wv*16 + ch*8;
  float ai[8] = {0,0,0,0,0,0,0,0}, ah[8] = {0,0,0,0,0,0,0,0};
  for (int j = 0; j < 64; j++){
    float4 h4 = { gT[j*4+0][b], gT[j*4+1][b], gT[j*4+2][b], gT[j*4+3][b] };
    #pragma unroll
    for (int vv = 0; vv < 8; vv++){
      float4 w4 = *(const float4*)(Wih + (size_t)(c0+vv)*1024 + ks*256 + j*4);
      ai[vv] = dot4(w4, h4, ai[vv]);
    }
  }
  for (int j = 0; j < 32; j++){
    float4 h4 = { hT[j*4+0][b], hT[j*4+1][b], hT[j*4+2][b], hT[j*4+3][b] };
    #pragma unroll
    for (int vv = 0; vv < 8; vv++){
      float4 w4 = *(const float4*)(Whh + (size_t)(c0+vv)*512 + ks*128 + j*4);
      ah[vv] = dot4(w4, h4, ah[vv]);
    }
  }
  #pragma unroll
  for (int vv = 0; vv < 8; vv++){
    float a = ai[vv] + (ks==0 ? bih[c0+vv] : 0.f);
    float h = ah[vv] + (ks==0 ? bhh[c0+vv] : 0.f);
    atomicAdd(ws + OFF_GI0 + b*H3_ + c0 + vv, a);
    atomicAdd(ws + OFF_GH0 + b*H3_ + c0 + vv, h);
  }
}

// ---------------------------------------------------------------- GRU1 gates (with inline h0-combine); grid 96
__global__ __launch_bounds__(256) void k_gates1(const float* __restrict__ Wih, const float* __restrict__ Whh,
    const float* __restrict__ bih, const float* __restrict__ bhh, float* __restrict__ ws)
{
  int cc = blockIdx.x % 24, ks = blockIdx.x / 24; // k-slice of 128
  int tid = threadIdx.x;
  __shared__ float h0T[128][32];
  __shared__ float h1T[128][32];
  for (int i = tid; i < 4096; i += 256){
    int b = i & 31, kk = i >> 5;
    int k = ks*128 + kk;
    float ir = ws[OFF_GI0 + b*H3_ + k],         hr = ws[OFF_GH0 + b*H3_ + k];
    float iz = ws[OFF_GI0 + b*H3_ + 512 + k],   hz = ws[OFF_GH0 + b*H3_ + 512 + k];
    float in_= ws[OFF_GI0 + b*H3_ + 1024 + k],  hn = ws[OFF_GH0 + b*H3_ + 1024 + k];
    float r = sigm(ir + hr), z = sigm(iz + hz);
    float n = tanh_(in_ + r*hn);
    float h0 = (1.f - z)*n + z*ws[OFF_HID + b*512 + k];
    h0T[kk][b] = h0;
    if (cc == 0) ws[OFF_H0N + b*512 + k] = h0;
  }
  {
    int b = tid & 31, kq = tid >> 5;
    for (int it = 0; it < 4; it++){
      int k = it*32 + kq*4;
      float4 v = *(const float4*)(ws + OFF_HID + 16384 + b*512 + ks*128 + k);
      h1T[k+0][b]=v.x; h1T[k+1][b]=v.y; h1T[k+2][b]=v.z; h1T[k+3][b]=v.w;
    }
  }
  __syncthreads();
  int lane = tid & 63, wv = tid >> 6;
  int b = lane & 31, ch = lane >> 5;
  int c0 = cc*64 + wv*16 + ch*8;
  float ai[8] = {0,0,0,0,0,0,0,0}, ah[8] = {0,0,0,0,0,0,0,0};
  for (int j = 0; j < 32; j++){
    float4 a4 = { h0T[j*4+0][b], h0T[j*4+1][b], h0T[j*4+2][b], h0T[j*4+3][b] };
    float4 b4 = { h1T[j*4+0][b], h1T[j*4+1][b], h1T[j*4+2][b], h1T[j*4+3][b] };
    #pragma unroll
    for (int vv = 0; vv < 8; vv++){
      float4 wi = *(const float4*)(Wih + (size_t)(c0+vv)*512 + ks*128 + j*4);
      ai[vv] = dot4(wi, a4, ai[vv]);
      float4 wh = *(const float4*)(Whh + (size_t)(c0+vv)*512 + ks*128 + j*4);
      ah[vv] = dot4(wh, b4, ah[vv]);
    }
  }
  #pragma unroll
  for (int vv = 0; vv < 8; vv++){
    float a = ai[vv] + (ks==0 ? bih[c0+vv] : 0.f);
    float h = ah[vv] + (ks==0 ? bhh[c0+vv] : 0.f);
    atomicAdd(ws + OFF_GI1 + b*H3_ + c0 + vv, a);
    atomicAdd(ws + OFF_GH1 + b*H3_ + c0 + vv, h);
  }
}

// ---------------------------------------------------------------- h1-combine + q gemm for NEXT step; grid 32 = 8cc x 4ks
__global__ __launch_bounds__(256) void k_hq(int init, const float* __restrict__ Wa,
    const float* __restrict__ ba, float* __restrict__ ws)
{
  int cc = blockIdx.x & 7, ks = blockIdx.x >> 3; // k-slice of 256 (of 1024 query dims)
  int tid = threadIdx.x;
  __shared__ float qT[256][32];
  if (!init && ks >= 2){
    for (int i = tid; i < 8192; i += 256){
      int b = i & 31, kk = i >> 5;
      int k = (ks - 2)*256 + kk;
      float ir = ws[OFF_GI1 + b*H3_ + k],        hr = ws[OFF_GH1 + b*H3_ + k];
      float iz = ws[OFF_GI1 + b*H3_ + 512 + k],  hz = ws[OFF_GH1 + b*H3_ + 512 + k];
      float in_= ws[OFF_GI1 + b*H3_ + 1024 + k], hn = ws[OFF_GH1 + b*H3_ + 1024 + k];
      float r = sigm(ir+hr), z = sigm(iz+hz);
      float n = tanh_(in_ + r*hn);
      float h1 = (1.f - z)*n + z*ws[OFF_HID + 16384 + b*512 + k];
      qT[kk][b] = h1;
      if (cc == 0) ws[OFF_H1N + b*512 + k] = h1;
    }
  } else {
    int b = tid & 31, kq = tid >> 5;
    const float* src;
    if (init) src = ws + OFF_HID + (ks >> 1)*16384 + (ks & 1)*256;
    else      src = ws + OFF_H0N + ks*256;
    for (int it = 0; it < 8; it++){
      int k = it*32 + kq*4;
      float4 v = *(const float4*)(src + b*512 + k);
      qT[k+0][b]=v.x; qT[k+1][b]=v.y; qT[k+2][b]=v.z; qT[k+3][b]=v.w;
    }
  }
  if (!init && ks < 2 && cc == 0){
    for (int i = tid; i < 8192; i += 256){
      int b = i & 31, kk = i >> 5;
      ws[OFF_HID + b*512 + ks*256 + kk] = ws[OFF_H0N + b*512 + ks*256 + kk];
    }
  }
  __syncthreads();
  int lane = tid & 63, wv = tid >> 6;
  int b = lane & 31, ch = lane >> 5;
  int c0 = cc*64 + wv*16 + ch*8;
  float acc[8] = {0,0,0,0,0,0,0,0};
  for (int j = 0; j < 64; j++){
    float4 h4 = { qT[j*4+0][b], qT[j*4+1][b], qT[j*4+2][b], qT[j*4+3][b] };
    #pragma unroll
    for (int vv = 0; vv < 8; vv++){
      float4 w4 = *(const float4*)(Wa + (size_t)(c0+vv)*1024 + ks*256 + j*4);
      acc[vv] = dot4(w4, h4, acc[vv]);
    }
  }
  #pragma unroll
  for (int vv = 0; vv < 8; vv++)
    atomicAdd(ws + OFF_Q + b*512 + c0 + vv, acc[vv] + (ks==0 ? ba[c0+vv] : 0.f));
}

// ---------------------------------------------------------------- logits + chunk stats; grid 500
// New structure: lane l owns k in {4l..4l+4} u {256+4l..+4}; weights coalesced (1KB/instr, read once);
// 4-row iterations; register butterfly (permlane32/16 + shfl for last 4 levels) to land C[v][b] on lanes.
#define R_(i) a[(i)>>5][(i)&31]
__global__ __launch_bounds__(256, 2) void k_logits(int t, const float* __restrict__ outW,
    const float* __restrict__ outb, float* __restrict__ ws, float* __restrict__ out)
{
  __shared__ float hT[32][512]; // [b][k] fp32, 64KB
  int tid = threadIdx.x;
  {
    const float4* src = (const float4*)(ws + OFF_H1N);
    float4* dst = (float4*)(&hT[0][0]);
    for (int i = tid; i < 4096; i += 256) dst[i] = src[i];
  }
  if (blockIdx.x == 0){
    for (int i = tid; i < 16384; i += 256) ws[OFF_HID + 16384 + i] = ws[OFF_H1N + i];
  }
  __syncthreads();

  int lane = tid & 63, wv = tid >> 6;
  int vbase = blockIdx.x*64 + wv*16;
  int rsel = lane >> 4;          // quad-row owned after butterfly
  int b0 = (lane & 15)*2;        // batch pair owned after butterfly

  float m0=-1e30f, se0=0.f, m1=-1e30f, se1=0.f;
  int idx0=0x7fffffff, idx1=0x7fffffff;

  const float* hrow = &hT[0][0] + lane*4;

  // prologue: load weights for iter 0
  float4 w[4][2], wn[4][2];
  #pragma unroll
  for (int r = 0; r < 4; r++){
    const float* wr = outW + (size_t)(vbase + r)*512 + lane*4;
    w[r][0] = *(const float4*)(wr);
    w[r][1] = *(const float4*)(wr + 256);
  }

  for (int it = 0; it < 4; it++){
    if (it < 3){
      #pragma unroll
      for (int r = 0; r < 4; r++){
        const float* wr = outW + (size_t)(vbase + (it+1)*4 + r)*512 + lane*4;
        wn[r][0] = *(const float4*)(wr);
        wn[r][1] = *(const float4*)(wr + 256);
      }
    }
    float a[4][32];
    #pragma unroll
    for (int b = 0; b < 32; b++){
      float4 h0 = *(const float4*)(hrow + b*512);
      float4 h1 = *(const float4*)(hrow + b*512 + 256);
      #pragma unroll
      for (int r = 0; r < 4; r++){
        float s = 0.f;
        s = dot4(w[r][0], h0, s);
        s = dot4(w[r][1], h1, s);
        a[r][b] = s;
      }
    }
    // ---- butterfly reduce 128 partials across 64 lanes ----
    // level xor32 (lane bit5): 128 -> 64, VALU permlane
    #pragma unroll
    for (int i = 0; i < 64; i++){
      float x = R_(i), y = R_(i+64);
      asm volatile("s_nop 1\n\tv_permlane32_swap_b32 %0, %1" : "+v"(x), "+v"(y));
      R_(i) = x + y;
    }
    // level xor16 (lane bit4): 64 -> 32
    #pragma unroll
    for (int i = 0; i < 32; i++){
      float x = R_(i), y = R_(i+32);
      asm volatile("s_nop 1\n\tv_permlane16_swap_b32 %0, %1" : "+v"(x), "+v"(y));
      R_(i) = x + y;
    }
    // levels xor8..xor1 (lane bits 3..0): 32 -> 2
    #pragma unroll
    for (int lb = 3; lb >= 0; lb--){
      int half = 1 << (lb + 1);
      bool bit = (lane >> lb) & 1;
      #pragma unroll
      for (int i = 0; i < (1 << (lb + 1)); i++){
        if (i < half){} // keep structure simple for unroller
      }
      #pragma unroll
      for (int i = 0; i < 16; i++){
        if (i < half){
          float keep = bit ? R_(i+half) : R_(i);
          float send = bit ? R_(i) : R_(i+half);
          R_(i) = keep + __shfl_xor(send, 1 << lb, 64);
        }
      }
    }
    // lane now holds C[v][b0], C[v][b0+1] with v = vbase+it*4+rsel
    int v = vbase + it*4 + rsel;
    float ob = outb[v];
    float x0 = R_(0) + ob;
    float x1 = R_(1) + ob;
    size_t obase = (size_t)OUT_LOGP + (size_t)b0*(T_*V_) + (size_t)t*V_ + v;
    out[obase] = x0;
    out[obase + (size_t)(T_*V_)] = x1;
    // running stats
    float M0 = fmaxf(m0, x0);
    se0 = se0*__expf(m0 - M0) + __expf(x0 - M0);
    if (x0 > m0) idx0 = v;
    m0 = M0;
    float M1 = fmaxf(m1, x1);
    se1 = se1*__expf(m1 - M1) + __expf(x1 - M1);
    if (x1 > m1) idx1 = v;
    m1 = M1;
    // rotate weight buffers (static copies)
    #pragma unroll
    for (int r = 0; r < 4; r++){ w[r][0] = wn[r][0]; w[r][1] = wn[r][1]; }
  }

  // combine stats across lanes sharing b0 (lane bits 4,5 = different v)
  #pragma unroll
  for (int d = 4; d <= 5; d++){
    int msk = 1 << d;
    float m2 = __shfl_xor(m0, msk, 64), s2 = __shfl_xor(se0, msk, 64);
    int   i2 = __shfl_xor(idx0, msk, 64);
    float M = fmaxf(m0, m2);
    se0 = se0*__expf(m0 - M) + s2*__expf(m2 - M);
    idx0 = (m2 > m0 || (m2 == m0 && i2 < idx0)) ? i2 : idx0;
    m0 = M;
    float m3 = __shfl_xor(m1, msk, 64), s3 = __shfl_xor(se1, msk, 64);
    int   i3 = __shfl_xor(idx1, msk, 64);
    float N = fmaxf(m1, m3);
    se1 = se1*__expf(m1 - N) + s3*__expf(m3 - N);
    idx1 = (m3 > m1 || (m3 == m1 && i3 < idx1)) ? i3 : idx1;
    m1 = N;
  }
  if (lane < 16){
    int chunk = blockIdx.x*4 + wv;
    ws[OFF_SMAX + chunk*32 + b0]   = m0;
    ws[OFF_SMAX + chunk*32 + b0+1] = m1;
    ws[OFF_SSUM + chunk*32 + b0]   = se0;
    ws[OFF_SSUM + chunk*32 + b0+1] = se1;
    ((int*)ws)[OFF_SIDX + chunk*32 + b0]   = idx0;
    ((int*)ws)[OFF_SIDX + chunk*32 + b0+1] = idx1;
  }
}

// ---------------------------------------------------------------- final stats (step 31 lse)
__global__ __launch_bounds__(256) void k_finstats(float* __restrict__ ws)
{
  __shared__ float rm[256], rs[256];
  __shared__ int   ri[256];
  int b = blockIdx.x; int token; float lse;
  stats_reduce(ws, b, threadIdx.x, rm, rs, ri, token, lse);
  if (threadIdx.x == 0) ws[OFF_LSE + 31*32 + b] = lse;
}

// ---------------------------------------------------------------- logits -> log_probs in place + final hidden copy
__global__ __launch_bounds__(256) void k_finout(const float* __restrict__ ws, float* __restrict__ out)
{
  if (blockIdx.x < 16000){
    size_t base = (size_t)blockIdx.x*2048 + (size_t)threadIdx.x*8;
    int b = (int)(base / ((size_t)T_*V_));
    int t = (int)((base / V_) % T_);
    float lse = ws[OFF_LSE + t*32 + b];
    float4* p = (float4*)(out + base);
    float4 x = p[0], y = p[1];
    x.x-=lse; x.y-=lse; x.z-=lse; x.w-=lse;
    y.x-=lse; y.y-=lse; y.z-=lse; y.w-=lse;
    p[0]=x; p[1]=y;
  } else {
    int i = (blockIdx.x - 16000)*2048 + threadIdx.x*8;
    const float4* s = (const float4*)(ws + OFF_HID + i);
    float4* d = (float4*)(out + OUT_HIDN + i);
    d[0] = s[0]; d[1] = s[1];
  }
}

// ---------------------------------------------------------------- launch
extern "C" void kernel_launch(void* const* d_in, const int* in_sizes, int n_in,
                              void* d_out, int out_size, void* d_ws, size_t ws_size,
                              hipStream_t stream)
{
  (void)in_sizes; (void)n_in; (void)out_size; (void)ws_size;
  const float* enc   = (const float*)d_in[0];
  const float* ehid  = (const float*)d_in[1];
  const float* emb   = (const float*)d_in[3];
  const float* Wa    = (const float*)d_in[4];
  const float* ba    = (const float*)d_in[5];
  const float* Ua    = (const float*)d_in[6];
  const float* bua   = (const float*)d_in[7];
  const float* Va    = (const float*)d_in[8];
  const float* bva   = (const float*)d_in[9];
  const float* g0Wih = (const float*)d_in[10];
  const float* g0Whh = (const float*)d_in[11];
  const float* g0bih = (const float*)d_in[12];
  const float* g0bhh = (const float*)d_in[13];
  const float* g1Wih = (const float*)d_in[14];
  const float* g1Whh = (const float*)d_in[15];
  const float* g1bih = (const float*)d_in[16];
  const float* g1bhh = (const float*)d_in[17];
  const float* outW  = (const float*)d_in[18];
  const float* outb  = (const float*)d_in[19];
  float* ws  = (float*)d_ws;
  float* out = (float*)d_out;

  hipLaunchKernelGGL(k_init,   dim3(128), dim3(256), 0, stream, ehid, ws);
  hipLaunchKernelGGL(k_ukeys,  dim3(256), dim3(256), 0, stream, enc, Ua, bua, ws);
  hipLaunchKernelGGL(k_hq,     dim3(32),  dim3(256), 0, stream, 1, Wa, ba, ws);
  for (int t = 0; t < T_; t++){
    hipLaunchKernelGGL(k_attn,   dim3(32),  dim3(256), 0, stream, t, emb, enc, Va, bva, ws, out);
    hipLaunchKernelGGL(k_gates0, dim3(96),  dim3(256), 0, stream, g0Wih, g0Whh, g0bih, g0bhh, ws);
    hipLaunchKernelGGL(k_gates1, dim3(96),  dim3(256), 0, stream, g1Wih, g1Whh, g1bih, g1bhh, ws);
    hipLaunchKernelGGL(k_hq,     dim3(32),  dim3(256), 0, stream, 0, Wa, ba, ws);
    hipLaunchKernelGGL(k_logits, dim3(500), dim3(256), 0, stream, t, outW, outb, ws, out);
  }
  hipLaunchKernelGGL(k_finstats, dim3(32),    dim3(256), 0, stream, ws);
  hipLaunchKernelGGL(k_finout,   dim3(16016), dim3(256), 0, stream, ws, out);
}